// Round 20
// baseline (540.738 us; speedup 1.0000x reference)
//
#include <hip/hip_runtime.h>
#include <hip/hip_bf16.h>
#include <math.h>

// ---- fixed problem dims ----
constexpr int Bb  = 16;
constexpr int Tt  = 16;
constexpr int Nn  = 196;   // patches (14x14)
constexpr int Cc  = 768;
constexpr int Aa  = 192;
constexpr int KK  = 8;     // TOPK
constexpr int NCAND = 16;  // fp32 candidates refined in f64
constexpr int NCH = 14;    // n-chunks for delta/fused parallelism
constexpr int BT  = Bb * Tt;            // 256
constexpr int BTN = BT * Nn;            // 50176
constexpr int BKT = Bb * KK * Tt;       // 2048 anchor-token rows
constexpr size_t SZ = (size_t)BTN * Aa; // 9,633,792 floats

typedef unsigned short ushortt;
typedef __attribute__((ext_vector_type(8))) short bf16x8;
typedef __attribute__((ext_vector_type(4))) float f32x4;
typedef __attribute__((ext_vector_type(4))) unsigned short u16x4;
typedef __attribute__((ext_vector_type(8))) unsigned short u16x8;

static __device__ __forceinline__ float gelu_f(float x) {
  return 0.5f * x * (1.0f + erff(x * 0.7071067811865476f));
}
static __device__ __forceinline__ ushortt f2bf(float f) {
  __hip_bfloat16 h = __float2bfloat16(f);
  return *reinterpret_cast<ushortt*>(&h);
}
static __device__ __forceinline__ float bf2f(ushortt u) {
  return __uint_as_float(((unsigned)u) << 16);
}
static __device__ __forceinline__ void gload16(const void* g, void* l) {
  __builtin_amdgcn_global_load_lds(
      (const __attribute__((address_space(1))) void*)g,
      (__attribute__((address_space(3))) void*)l, 16, 0, 0);
}

// ---- weight pre-convert offsets ----
constexpr int S_down   = Aa * Cc;
constexpr int S_attnin = 3 * Aa * Aa;
constexpr int S_sq     = Aa * Aa;
constexpr int S_t      = 2 * Aa * Aa;
constexpr int O1 = S_down;
constexpr int O2 = O1 + S_attnin;
constexpr int O3 = O2 + S_sq;
constexpr int O4 = O3 + S_sq;
constexpr int O5 = O4 + S_sq;
constexpr int O6 = O5 + S_sq;
constexpr int O7 = O6 + S_t;
constexpr int O8 = O7 + S_t;
constexpr int OTOT = O8 + S_down;  // 700416

__global__ void cvtw_kernel(const float* __restrict__ w0,
                            const float* __restrict__ w1,
                            const float* __restrict__ w2,
                            const float* __restrict__ w3,
                            const float* __restrict__ w4,
                            const float* __restrict__ w5,
                            const float* __restrict__ w6,
                            const float* __restrict__ w7,
                            const float* __restrict__ w8,
                            ushortt* __restrict__ outw) {
  int e = blockIdx.x * 256 + threadIdx.x;
  const float* src;
  int off;
  if (e < O1)      { src = w0; off = 0;  }
  else if (e < O2) { src = w1; off = O1; }
  else if (e < O3) { src = w2; off = O2; }
  else if (e < O4) { src = w3; off = O3; }
  else if (e < O5) { src = w4; off = O4; }
  else if (e < O6) { src = w5; off = O5; }
  else if (e < O7) { src = w6; off = O6; }
  else if (e < O8) { src = w7; off = O7; }
  else             { src = w8; off = O8; }
  outw[e] = f2bf(src[e - off]);
}

// ============================================================
// shared epilogue helper macro (coalesced stores via LDS)
// ============================================================
#define GEMM_EPILOGUE(smem_, row0_, col0_, Nc_)                              \
  do {                                                                       \
    constexpr int EP = 100;                                                  \
    float* epi = (float*)(smem_);                                            \
    _Pragma("unroll") for (int fm = 0; fm < 2; ++fm) {                       \
      int rl = wr * 32 + fm * 16 + kgrp * 4;                                 \
      _Pragma("unroll") for (int fn = 0; fn < 3; ++fn) {                     \
        int cl = wc * 48 + fn * 16 + l15;                                    \
        _Pragma("unroll") for (int j = 0; j < 4; ++j)                        \
            epi[(rl + j) * EP + cl] = acc[fm][fn][j];                        \
      }                                                                      \
    }                                                                        \
    __syncthreads();                                                         \
    _Pragma("unroll") for (int it = 0; it < 6; ++it) {                       \
      int f = it * 256 + tid;                                                \
      int r = f / 24, c4 = f - r * 24;                                       \
      float4 v = *(const float4*)&epi[r * EP + c4 * 4];                      \
      int c = (col0_) + c4 * 4;                                              \
      if (BIAS) {                                                            \
        float4 bv = *(const float4*)(bias + c);                              \
        v.x += bv.x; v.y += bv.y; v.z += bv.z; v.w += bv.w;                  \
      }                                                                      \
      if (EPI == 1) {                                                        \
        v.x = gelu_f(v.x); v.y = gelu_f(v.y);                                \
        v.z = gelu_f(v.z); v.w = gelu_f(v.w);                                \
      }                                                                      \
      int R = (row0_) + r;                                                   \
      if constexpr (EPI == 2) {                                              \
        int bt2 = R / Nn, n2 = R - bt2 * Nn;                                 \
        size_t off = (size_t)(bt2 * (Nn + 1) + 1 + n2) * (Nc_) + c;          \
        float4 rv = *(const float4*)(resid + off);                           \
        v.x += rv.x; v.y += rv.y; v.z += rv.z; v.w += rv.w;                  \
        *(float4*)((float*)Cout + off) = v;                                  \
      } else if constexpr (sizeof(CT) == 4) {                                \
        *(float4*)((float*)Cout + (size_t)R * (Nc_) + c) = v;                \
      } else {                                                               \
        u16x4 ob = {f2bf(v.x), f2bf(v.y), f2bf(v.z), f2bf(v.w)};             \
        *(u16x4*)((ushortt*)Cout + (size_t)R * (Nc_) + c) = ob;              \
      }                                                                      \
    }                                                                        \
  } while (0)

// ============================================================
// gemm_k192 (r20): K=192 single-shot -- all 15 gloads issued at
// once (3 k-sections x (A:2 + B:3)), ONE barrier, 36 MFMAs straight
// through. Same k-order as gemm_lds => bit-identical arithmetic.
// LDS 61.4 KB (A 3x[64][64] + B 3x[96][64], XOR-swizzled reads).
// ============================================================
template <typename CT, int BIAS, int EPI>
__global__ __launch_bounds__(256) void gemm_k192(
    const ushortt* __restrict__ Ain, const ushortt* __restrict__ Wb,
    const float* __restrict__ bias, CT* __restrict__ Cout,
    const float* __restrict__ resid, int M, int Nc) {
  constexpr int K = 192;
  __shared__ __align__(16) unsigned char smem[61440];
  ushortt* As = (ushortt*)smem;            // section stride 4096 elems
  ushortt* Bs = (ushortt*)(smem + 24576);  // section stride 6144 elems
  const int tid = threadIdx.x;

  const int ncb = gridDim.x;
  const int nwg = ncb * gridDim.y;
  const int bid = blockIdx.y * ncb + blockIdx.x;
  const int cpx = nwg >> 3;
  const int swz = (bid & 7) * cpx + (bid >> 3);
  const int row0 = (swz / ncb) * 64;
  const int col0 = (swz % ncb) * 96;

  const int wid = tid >> 6;
  const int lane = tid & 63;
  const int wr = wid >> 1;
  const int wc = wid & 1;
  const int l15 = lane & 15;
  const int kgrp = lane >> 4;

  const int lr = lane >> 3;
  const int lc = 8 * ((lane & 7) ^ lr);

  f32x4 acc[2][3];
#pragma unroll
  for (int i = 0; i < 2; ++i)
#pragma unroll
    for (int j = 0; j < 3; ++j) acc[i][j] = (f32x4){0.f, 0.f, 0.f, 0.f};

  // issue ALL staging loads (15 per wave), maximum MLP, one drain
#pragma unroll
  for (int s = 0; s < 3; ++s) {
#pragma unroll
    for (int i = 0; i < 2; ++i) {
      int j = 2 * wid + i;
      const ushortt* g = Ain + (size_t)(row0 + 8 * j + lr) * K + s * 64 + lc;
      gload16(g, As + s * 4096 + j * 512);
    }
#pragma unroll
    for (int i = 0; i < 3; ++i) {
      int j = 3 * wid + i;
      const ushortt* g = Wb + (size_t)(col0 + 8 * j + lr) * K + s * 64 + lc;
      gload16(g, Bs + s * 6144 + j * 512);
    }
  }
  __syncthreads();

#pragma unroll
  for (int kk = 0; kk < 6; ++kk) {
    const int sec = kk >> 1;
    const int cb = (kk & 1) * 64 + kgrp * 16;
    bf16x8 af[2], bfv[3];
#pragma unroll
    for (int fm = 0; fm < 2; ++fm) {
      int r = wr * 32 + fm * 16 + l15;
      af[fm] = *(const bf16x8*)&As[sec * 4096 + r * 64 +
                                   ((cb ^ ((r & 7) << 4)) >> 1)];
    }
#pragma unroll
    for (int fn = 0; fn < 3; ++fn) {
      int r = wc * 48 + fn * 16 + l15;
      bfv[fn] = *(const bf16x8*)&Bs[sec * 6144 + r * 64 +
                                    ((cb ^ ((r & 7) << 4)) >> 1)];
    }
#pragma unroll
    for (int fm = 0; fm < 2; ++fm)
#pragma unroll
      for (int fn = 0; fn < 3; ++fn)
        acc[fm][fn] = __builtin_amdgcn_mfma_f32_16x16x32_bf16(
            af[fm], bfv[fn], acc[fm][fn], 0, 0, 0);
  }
  __syncthreads();  // all waves done reading A/B before epi overwrite

  GEMM_EPILOGUE(smem, row0, col0, Nc);
}

// ============================================================
// gemm_lds (r15): bf16 A & W via global_load_lds, XOR swizzle.
// (kept for K=384 tmlp2)
// ============================================================
template <typename CT, int BIAS, int EPI>
__global__ __launch_bounds__(256) void gemm_lds(
    const ushortt* __restrict__ Ain, const ushortt* __restrict__ Wb,
    const float* __restrict__ bias, CT* __restrict__ Cout,
    const float* __restrict__ resid, int M, int Nc, int K) {
  __shared__ __align__(16) unsigned char smem[40960];
  ushortt (*As)[64 * 64] = (ushortt(*)[64 * 64])smem;
  ushortt (*Bs)[96 * 64] = (ushortt(*)[96 * 64])(smem + 2 * 64 * 64 * 2);
  const int tid = threadIdx.x;

  const int ncb = gridDim.x;
  const int nwg = ncb * gridDim.y;
  const int bid = blockIdx.y * ncb + blockIdx.x;
  const int cpx = nwg >> 3;
  const int swz = (bid & 7) * cpx + (bid >> 3);
  const int row0 = (swz / ncb) * 64;
  const int col0 = (swz % ncb) * 96;

  const int wid = tid >> 6;
  const int lane = tid & 63;
  const int wr = wid >> 1;
  const int wc = wid & 1;
  const int l15 = lane & 15;
  const int kgrp = lane >> 4;

  const int lr = lane >> 3;
  const int lc = 8 * ((lane & 7) ^ lr);

  f32x4 acc[2][3];
#pragma unroll
  for (int i = 0; i < 2; ++i)
#pragma unroll
    for (int j = 0; j < 3; ++j) acc[i][j] = (f32x4){0.f, 0.f, 0.f, 0.f};

#define ISSUE(buf, k0)                                                       \
  do {                                                                       \
    _Pragma("unroll") for (int i = 0; i < 2; ++i) {                          \
      int j = 2 * wid + i;                                                   \
      const ushortt* g =                                                     \
          Ain + (size_t)(row0 + 8 * j + lr) * K + (k0) + lc;                 \
      gload16(g, &As[buf][j * 512]);                                         \
    }                                                                        \
    _Pragma("unroll") for (int i = 0; i < 3; ++i) {                          \
      int j = 3 * wid + i;                                                   \
      const ushortt* g =                                                     \
          Wb + (size_t)(col0 + 8 * j + lr) * K + (k0) + lc;                  \
      gload16(g, &Bs[buf][j * 512]);                                         \
    }                                                                        \
  } while (0)

  ISSUE(0, 0);
  __syncthreads();

  const int nsteps = K >> 6;
  int cur = 0;
  for (int step = 0; step < nsteps; ++step) {
    const bool pref = (step + 1 < nsteps);
    if (pref) ISSUE(cur ^ 1, (step + 1) << 6);
#pragma unroll
    for (int kk = 0; kk < 2; ++kk) {
      const int cb = kk * 64 + kgrp * 16;
      bf16x8 af[2], bfv[3];
#pragma unroll
      for (int fm = 0; fm < 2; ++fm) {
        int r = wr * 32 + fm * 16 + l15;
        af[fm] = *(const bf16x8*)&As[cur][r * 64 +
                                          ((cb ^ ((r & 7) << 4)) >> 1)];
      }
#pragma unroll
      for (int fn = 0; fn < 3; ++fn) {
        int r = wc * 48 + fn * 16 + l15;
        bfv[fn] = *(const bf16x8*)&Bs[cur][r * 64 +
                                           ((cb ^ ((r & 7) << 4)) >> 1)];
      }
#pragma unroll
      for (int fm = 0; fm < 2; ++fm)
#pragma unroll
        for (int fn = 0; fn < 3; ++fn)
          acc[fm][fn] = __builtin_amdgcn_mfma_f32_16x16x32_bf16(
              af[fm], bfv[fn], acc[fm][fn], 0, 0, 0);
    }
    __syncthreads();
    cur ^= 1;
  }
#undef ISSUE

  GEMM_EPILOGUE(smem, row0, col0, Nc);
}

// ============================================================
// gemm_hyb (r16): fp32 A reg-staged (pitched), bf16 W via gload.
// ============================================================
template <int ROWMAP, typename CT, int BIAS, int EPI>
__global__ __launch_bounds__(256) void gemm_hyb(
    const float* __restrict__ Ain, const ushortt* __restrict__ Wb,
    const float* __restrict__ bias, CT* __restrict__ Cout,
    const float* __restrict__ resid, int M, int Nc, int K) {
  constexpr int PIT = 72;
  __shared__ __align__(16) unsigned char smem[43008];
  ushortt (*As)[64 * PIT] = (ushortt(*)[64 * PIT])smem;
  ushortt (*Bs)[96 * 64] = (ushortt(*)[96 * 64])(smem + 18432);
  const int tid = threadIdx.x;

  const int ncb = gridDim.x;
  const int nwg = ncb * gridDim.y;
  const int bid = blockIdx.y * ncb + blockIdx.x;
  const int cpx = nwg >> 3;
  const int swz = (bid & 7) * cpx + (bid >> 3);
  const int row0 = (swz / ncb) * 64;
  const int col0 = (swz % ncb) * 96;

  const int wid = tid >> 6;
  const int lane = tid & 63;
  const int wr = wid >> 1;
  const int wc = wid & 1;
  const int l15 = lane & 15;
  const int kgrp = lane >> 4;

  const int q16 = tid & 15;
  const int lr = lane >> 3;
  const int lc = 8 * ((lane & 7) ^ lr);

  const int nsteps = K >> 6;

  const float* arowf[4];
#pragma unroll
  for (int p = 0; p < 4; ++p) {
    int r = row0 + (tid >> 4) + 16 * p;
    if (ROWMAP) {
      int bt = r / Nn;
      int n = r - bt * Nn;
      arowf[p] = Ain + (size_t)(bt * (Nn + 1) + 1 + n) * K;
    } else {
      arowf[p] = Ain + (size_t)r * K;
    }
  }

  f32x4 acc[2][3];
#pragma unroll
  for (int i = 0; i < 2; ++i)
#pragma unroll
    for (int j = 0; j < 3; ++j) acc[i][j] = (f32x4){0.f, 0.f, 0.f, 0.f};

  float4 apre[4];

#define ISSUE_B(buf, k0)                                                     \
  do {                                                                       \
    _Pragma("unroll") for (int i = 0; i < 3; ++i) {                          \
      int j = 3 * wid + i;                                                   \
      const ushortt* g =                                                     \
          Wb + (size_t)(col0 + 8 * j + lr) * K + (k0) + lc;                  \
      gload16(g, &Bs[buf][j * 512]);                                         \
    }                                                                        \
  } while (0)

#define STAGE_LOAD_A(k0)                                                     \
  _Pragma("unroll") for (int p = 0; p < 4; ++p)                              \
      apre[p] = *(const float4*)(arowf[p] + (k0) + q16 * 4);

#define STAGE_WRITE_A(buf)                                                   \
  _Pragma("unroll") for (int p = 0; p < 4; ++p) {                            \
    u16x4 b = {f2bf(apre[p].x), f2bf(apre[p].y), f2bf(apre[p].z),            \
               f2bf(apre[p].w)};                                             \
    *(u16x4*)&As[buf][((tid >> 4) + 16 * p) * PIT + q16 * 4] = b;            \
  }

  ISSUE_B(0, 0);
  STAGE_LOAD_A(0);
  STAGE_WRITE_A(0);
  __syncthreads();

  int cur = 0;
  for (int step = 0; step < nsteps; ++step) {
    const bool pref = (step + 1 < nsteps);
    if (pref) {
      int k0 = (step + 1) << 6;
      ISSUE_B(cur ^ 1, k0);
      STAGE_LOAD_A(k0);
    }
#pragma unroll
    for (int kk = 0; kk < 2; ++kk) {
      const int cb = kk * 64 + kgrp * 16;
      bf16x8 af[2], bfv[3];
#pragma unroll
      for (int fm = 0; fm < 2; ++fm)
        af[fm] = *(const bf16x8*)&As[cur][(wr * 32 + fm * 16 + l15) * PIT +
                                          kk * 32 + kgrp * 8];
#pragma unroll
      for (int fn = 0; fn < 3; ++fn) {
        int r = wc * 48 + fn * 16 + l15;
        bfv[fn] = *(const bf16x8*)&Bs[cur][r * 64 +
                                           ((cb ^ ((r & 7) << 4)) >> 1)];
      }
#pragma unroll
      for (int fm = 0; fm < 2; ++fm)
#pragma unroll
        for (int fn = 0; fn < 3; ++fn)
          acc[fm][fn] = __builtin_amdgcn_mfma_f32_16x16x32_bf16(
              af[fm], bfv[fn], acc[fm][fn], 0, 0, 0);
    }
    if (pref) {
      STAGE_WRITE_A(cur ^ 1);
    }
    __syncthreads();
    cur ^= 1;
  }
#undef ISSUE_B
#undef STAGE_LOAD_A
#undef STAGE_WRITE_A

  GEMM_EPILOGUE(smem, row0, col0, Nc);
}

// ============================================================
// delta14 (r17)
// ============================================================
__global__ __launch_bounds__(192) void delta14_kernel(
    const ushortt* __restrict__ ph, ushortt* __restrict__ delta,
    float* __restrict__ dppart2, float* __restrict__ sal) {
  int blk = blockIdx.x;
  int bt = blk / NCH, chunk = blk - bt * NCH;
  int t = bt & 15;
  int a = threadIdx.x;
  int n0 = chunk * 14;
  __shared__ float spart[3][14];
  const ushortt* cur = ph + ((size_t)bt * Nn + n0) * Aa + a;
  ushortt* dl = delta + ((size_t)bt * Nn + n0) * Aa + a;
  int wv = a >> 6, ln = a & 63;
  float acc = 0.f;
  if (t == 0) {
    for (int i = 0; i < 14; ++i) dl[(size_t)i * Aa] = 0;
    if (a < 14) sal[(size_t)bt * Nn + n0 + a] = 0.f;
    dppart2[(size_t)blk * Aa + a] = 0.f;
    return;
  }
  const ushortt* prev = cur - (size_t)Nn * Aa;
  for (int i = 0; i < 14; ++i) {
    float d = bf2f(cur[(size_t)i * Aa]) - bf2f(prev[(size_t)i * Aa]);
    dl[(size_t)i * Aa] = f2bf(d);
    float ad = fabsf(d);
    acc += ad;
    float s = ad;
#pragma unroll
    for (int off = 32; off > 0; off >>= 1) s += __shfl_xor(s, off, 64);
    if (ln == 0) spart[wv][i] = s;
  }
  dppart2[(size_t)blk * Aa + a] = acc;
  __syncthreads();
  if (a < 14)
    sal[(size_t)bt * Nn + n0 + a] =
        (spart[0][a] + spart[1][a] + spart[2][a]) * (1.0f / 192.0f);
}

// ============================================================
// top-16 fp32 candidates per (b,t)
// ============================================================
__global__ void topcand_kernel(const float* __restrict__ sal,
                               int* __restrict__ cand) {
  int bt = blockIdx.x;
  int lane = threadIdx.x;
  unsigned long long key[4];
#pragma unroll
  for (int j = 0; j < 4; ++j) {
    int n = lane + 64 * j;
    if (n < Nn) {
      unsigned fb = __float_as_uint(sal[(size_t)bt * Nn + n]);
      key[j] = ((unsigned long long)fb << 32) |
               (unsigned long long)(0xFFFFFFFFu - (unsigned)n);
    } else {
      key[j] = 0ULL;
    }
  }
  for (int r = 0; r < NCAND; ++r) {
    unsigned long long m = key[0];
    if (key[1] > m) m = key[1];
    if (key[2] > m) m = key[2];
    if (key[3] > m) m = key[3];
#pragma unroll
    for (int off = 32; off > 0; off >>= 1) {
      unsigned long long o = __shfl_xor(m, off, 64);
      if (o > m) m = o;
    }
    if (lane == 0)
      cand[bt * NCAND + r] = (int)(0xFFFFFFFFu - (unsigned)(m & 0xFFFFFFFFull));
#pragma unroll
    for (int j = 0; j < 4; ++j)
      if (key[j] == m) key[j] = 0ULL;
  }
}

// one-time transpose: wT[c][a] = down_w[a][c]
__global__ void transpose_w(const float* __restrict__ w,
                            float* __restrict__ wT) {
  int e = blockIdx.x * 256 + threadIdx.x;
  int c = e / Aa, a = e - c * Aa;
  wT[e] = w[(size_t)a * Cc + c];
}

// ============================================================
// f64 refine (r7)
// ============================================================
__global__ __launch_bounds__(192) void refine_kernel(
    const float* __restrict__ x, const float* __restrict__ wT,
    const int* __restrict__ cand, double* __restrict__ sal64) {
  int bt = blockIdx.x;
  int grp = blockIdx.y;
  int t = bt & 15;
  int a = threadIdx.x;
  if (t == 0) {
    if (a < 8) sal64[bt * NCAND + grp * 8 + a] = 0.0;
    return;
  }
  __shared__ double sdiff[8][Cc];
  const float* xt = x + ((size_t)bt * (Nn + 1) + 1) * Cc;
  const float* xp = xt - (size_t)(Nn + 1) * Cc;
  for (int g = 0; g < 8; ++g) {
    int n = cand[bt * NCAND + grp * 8 + g];
    const float* rt = xt + (size_t)n * Cc;
    const float* rp = xp + (size_t)n * Cc;
    for (int c = a; c < Cc; c += 192)
      sdiff[g][c] = (double)rt[c] - (double)rp[c];
  }
  __syncthreads();
  double acc[8] = {};
  for (int c = 0; c < Cc; ++c) {
    double wv = (double)wT[(size_t)c * Aa + a];
#pragma unroll
    for (int g = 0; g < 8; ++g) acc[g] = fma(wv, sdiff[g][c], acc[g]);
  }
  __shared__ double part[3][8];
  int wvx = a >> 6, ln = a & 63;
#pragma unroll
  for (int g = 0; g < 8; ++g) {
    double v = fabs(acc[g]);
#pragma unroll
    for (int off = 32; off > 0; off >>= 1) v += __shfl_xor(v, off, 64);
    if (ln == 0) part[wvx][g] = v;
  }
  __syncthreads();
  if (a < 8) {
    double s = part[0][a] + part[1][a] + part[2][a];
    sal64[bt * NCAND + grp * 8 + a] = s * (1.0 / 192.0);
  }
}

// final top-8 (r14 wave-parallel)
__global__ void select_kernel(const double* __restrict__ sal64,
                              const int* __restrict__ cand,
                              int* __restrict__ idx) {
  int bt = blockIdx.x;
  int t = bt & 15;
  int lane = threadIdx.x;
  if (t == 0) {
    if (lane < KK) idx[bt * KK + lane] = lane;
    return;
  }
  double v = (lane < NCAND) ? sal64[bt * NCAND + lane] : -1.0;
  int n = (lane < NCAND) ? cand[bt * NCAND + lane] : 0x7FFFFFFF;
  for (int r = 0; r < KK; ++r) {
    double bv = v;
    int bn = n, bl = lane;
#pragma unroll
    for (int off = 8; off >= 1; off >>= 1) {
      double ov = __shfl_xor(bv, off, 64);
      int on = __shfl_xor(bn, off, 64);
      int ol = __shfl_xor(bl, off, 64);
      if (ov > bv || (ov == bv && on < bn)) { bv = ov; bn = on; bl = ol; }
    }
    if (lane == 0) idx[bt * KK + r] = bn;
    if (lane == bl) v = -1.0;
  }
}

// ============================================================
// anchor attention pieces
// ============================================================
__global__ void gather_kernel(const ushortt* __restrict__ ph,
                              const ushortt* __restrict__ delta,
                              const int* __restrict__ idx,
                              ushortt* __restrict__ tok) {
  int row = blockIdx.x;
  int t = row & 15;
  int bk = row >> 4;
  int b = bk >> 3, k = bk & 7;
  int a = threadIdx.x;
  int n = idx[(b * 16 + t) * KK + k];
  size_t off = ((size_t)(b * 16 + t) * Nn + n) * Aa + a;
  tok[(size_t)row * Aa + a] = f2bf(bf2f(ph[off]) + bf2f(delta[off]));
}

__global__ __launch_bounds__(256) void attn_core(
    const float* __restrict__ qkv, float* __restrict__ o) {
  constexpr int P = 580;
  __shared__ float sq[16 * P];
  __shared__ float ssc[4][16][17];
  int bk = blockIdx.x;
  int tid = threadIdx.x;
  const float* src = qkv + (size_t)bk * 16 * 576;
  for (int e = tid; e < 16 * 144; e += 256) {
    int r = e / 144, c4 = e % 144;
    float4 v = *(const float4*)(src + r * 576 + c4 * 4);
    *(float4*)(&sq[r * P + c4 * 4]) = v;
  }
  __syncthreads();
  int h = tid >> 6, lane = tid & 63;
#pragma unroll
  for (int s4 = 0; s4 < 4; ++s4) {
    int e = lane + 64 * s4;
    int i = e >> 4, j = e & 15;
    const float* q = sq + i * P + h * 48;
    const float* k2 = sq + j * P + 192 + h * 48;
    float s = 0.f;
#pragma unroll
    for (int d = 0; d < 48; ++d) s = fmaf(q[d], k2[d], s);
    ssc[h][i][j] = s * 0.14433756729740643f;
  }
  __syncthreads();
  if (lane < 16) {
    float* r = ssc[h][lane];
    float mx = r[0];
    for (int j = 1; j < 16; ++j) mx = fmaxf(mx, r[j]);
    float sum = 0.f;
    for (int j = 0; j < 16; ++j) {
      float ev = expf(r[j] - mx);
      r[j] = ev;
      sum += ev;
    }
    float inv = 1.0f / sum;
    for (int j = 0; j < 16; ++j) r[j] *= inv;
  }
  __syncthreads();
#pragma unroll
  for (int s4 = 0; s4 < 12; ++s4) {
    int e = lane + 64 * s4;
    int i = e / 48, d = e - i * 48;
    float s = 0.f;
#pragma unroll
    for (int j = 0; j < 16; ++j)
      s = fmaf(ssc[h][i][j], sq[j * P + 384 + h * 48 + d], s);
    o[((size_t)bk * 16 + i) * 192 + h * 48 + d] = s;
  }
}

__global__ void appart_kernel(const float* __restrict__ attout,
                              float* __restrict__ appart) {
  int bk = blockIdx.x;
  int a = threadIdx.x;
  float s = 0.f;
  for (int t = 0; t < Tt; ++t)
    s += attout[((size_t)bk * Tt + t) * Aa + a];
  appart[bk * Aa + a] = s;
}

__global__ void ln32_kernel(float* __restrict__ buf,
                            const float* __restrict__ g,
                            const float* __restrict__ bb) {
  size_t row = (size_t)blockIdx.x * 4 + (threadIdx.x >> 6);
  int lane = threadIdx.x & 63;
  float* p = buf + row * Aa;
  float v0 = p[lane], v1 = p[lane + 64], v2 = p[lane + 128];
  float s = v0 + v1 + v2;
#pragma unroll
  for (int off = 32; off > 0; off >>= 1) s += __shfl_xor(s, off, 64);
  float m = s * (1.0f / 192.0f);
  float d0 = v0 - m, d1 = v1 - m, d2 = v2 - m;
  float ss = d0 * d0 + d1 * d1 + d2 * d2;
#pragma unroll
  for (int off = 32; off > 0; off >>= 1) ss += __shfl_xor(ss, off, 64);
  float inv = rsqrtf(ss * (1.0f / 192.0f) + 1e-5f);
  p[lane] = d0 * inv * g[lane] + bb[lane];
  p[lane + 64] = d1 * inv * g[lane + 64] + bb[lane + 64];
  p[lane + 128] = d2 * inv * g[lane + 128] + bb[lane + 128];
}

// depthwise 3x3 SAME conv + gelu; bf16
__global__ void conv2d_kernel(const ushortt* __restrict__ ph,
                              const float* __restrict__ ldw,
                              ushortt* __restrict__ og) {
  size_t e = (size_t)blockIdx.x * 256 + threadIdx.x;
  int a = (int)(e % Aa);
  size_t r = e / Aa;
  int n = (int)(r % Nn);
  int bt = (int)(r / Nn);
  int y = n / 14, x = n % 14;
  const ushortt* base = ph + (size_t)bt * Nn * Aa + a;
  const float* w = ldw + a * 9;
  float s = 0.f;
#pragma unroll
  for (int dy = -1; dy <= 1; ++dy) {
    int yy = y + dy;
    if (yy < 0 || yy >= 14) continue;
#pragma unroll
    for (int dx = -1; dx <= 1; ++dx) {
      int xc = x + dx;
      if (xc < 0 || xc >= 14) continue;
      s = fmaf(bf2f(base[(size_t)(yy * 14 + xc) * Aa]),
               w[(dy + 1) * 3 + (dx + 1)], s);
    }
  }
  og[e] = f2bf(gelu_f(s));
}

// depthwise k=3 conv over t + gelu; bf16
__global__ void conv1d_kernel(const ushortt* __restrict__ delta,
                              const float* __restrict__ tdw,
                              ushortt* __restrict__ og) {
  size_t e = (size_t)blockIdx.x * 256 + threadIdx.x;
  int a = (int)(e % Aa);
  size_t r = e / Aa;
  int n = (int)(r % Nn);
  int bt = (int)(r / Nn);
  int t = bt & 15, b = bt >> 4;
  const float* w = tdw + a * 3;
  float s = 0.f;
#pragma unroll
  for (int j = 0; j < 3; ++j) {
    int tt = t + j - 1;
    if (tt >= 0 && tt < Tt)
      s = fmaf(bf2f(delta[((size_t)(b * Tt + tt) * Nn + n) * Aa + a]), w[j], s);
  }
  og[e] = f2bf(gelu_f(s));
}

// in-place bf16 LayerNorm; one wave per row
__global__ void ln_kernel(ushortt* __restrict__ buf,
                          const float* __restrict__ g,
                          const float* __restrict__ bb) {
  size_t row = (size_t)blockIdx.x * 4 + (threadIdx.x >> 6);
  int lane = threadIdx.x & 63;
  ushortt* p = buf + row * Aa;
  float v0 = bf2f(p[lane]), v1 = bf2f(p[lane + 64]), v2 = bf2f(p[lane + 128]);
  float s = v0 + v1 + v2;
#pragma unroll
  for (int off = 32; off > 0; off >>= 1) s += __shfl_xor(s, off, 64);
  float m = s * (1.0f / 192.0f);
  float d0 = v0 - m, d1 = v1 - m, d2 = v2 - m;
  float ss = d0 * d0 + d1 * d1 + d2 * d2;
#pragma unroll
  for (int off = 32; off > 0; off >>= 1) ss += __shfl_xor(ss, off, 64);
  float inv = rsqrtf(ss * (1.0f / 192.0f) + 1e-5f);
  p[lane] = f2bf(d0 * inv * g[lane] + bb[lane]);
  p[lane + 64] = f2bf(d1 * inv * g[lane + 64] + bb[lane + 64]);
  p[lane + 128] = f2bf(d2 * inv * g[lane + 128] + bb[lane + 128]);
}

// posmap[bt*Nn + idx[bt,k]] = k+1
__global__ void scatter_pos(const int* __restrict__ idx,
                            short* __restrict__ posmap) {
  int bt = blockIdx.x;
  int k = threadIdx.x;
  if (k < KK) posmap[bt * Nn + idx[bt * KK + k]] = (short)(k + 1);
}

// gate MLP + 3-way softmax; dppart2 has NCH partials per bt
__global__ void gate_kernel(const float* __restrict__ dppart2,
                            const float* __restrict__ appart,
                            const float* __restrict__ w1,
                            const float* __restrict__ b1,
                            const float* __restrict__ w2,
                            const float* __restrict__ b2,
                            float* __restrict__ gw) {
  int b = blockIdx.x;
  __shared__ float sg[2 * Aa];
  __shared__ float sh[Aa];
  int tid = threadIdx.x;
  {
    float d = 0.f;
    for (int t2 = 0; t2 < Tt * NCH; ++t2)
      d += dppart2[(size_t)(b * Tt * NCH + t2) * Aa + tid];
    sg[tid] = d * (1.0f / 3136.0f);
    float a = 0.f;
    for (int k2 = 0; k2 < KK; ++k2) a += appart[(b * KK + k2) * Aa + tid];
    sg[Aa + tid] = a * (1.0f / 128.0f);
  }
  __syncthreads();
  {
    const float* w = w1 + (size_t)tid * 2 * Aa;
    float s = b1[tid];
#pragma unroll 8
    for (int j = 0; j < 2 * Aa; ++j) s = fmaf(sg[j], w[j], s);
    sh[tid] = gelu_f(s);
  }
  __syncthreads();
  float v[3];
#pragma unroll
  for (int i = 0; i < 3; ++i) {
    const float* w = w2 + (size_t)(i * Aa + tid) * Aa;
    float s = b2[i * Aa + tid];
#pragma unroll 8
    for (int j = 0; j < Aa; ++j) s = fmaf(sh[j], w[j], s);
    v[i] = s;
  }
  float mx = fmaxf(v[0], fmaxf(v[1], v[2]));
  float e0 = expf(v[0] - mx), e1 = expf(v[1] - mx), e2 = expf(v[2] - mx);
  float inv = 1.0f / (e0 + e1 + e2);
  gw[(b * 3 + 0) * Aa + tid] = e0 * inv;
  gw[(b * 3 + 1) * Aa + tid] = e1 * inv;
  gw[(b * 3 + 2) * Aa + tid] = e2 * inv;
}

// ============================================================
// fused14 (r17)
// ============================================================
__global__ __launch_bounds__(192) void fused14_kernel(
    const ushortt* __restrict__ local, const ushortt* __restrict__ trans,
    const float* __restrict__ attln, const short* __restrict__ posmap,
    const float* __restrict__ anb, const float* __restrict__ gw,
    ushortt* __restrict__ fused, float* __restrict__ fpart) {
  int blk = blockIdx.x;
  int bt = blk / NCH, chunk = blk - bt * NCH;
  int b = bt >> 4, t = bt & 15;
  int a = threadIdx.x;
  int n0 = chunk * 14;
  float g0 = gw[(b * 3 + 0) * Aa + a];
  float g1 = gw[(b * 3 + 1) * Aa + a];
  float g2 = gw[(b * 3 + 2) * Aa + a];
  float ab = anb[a];
  size_t base = ((size_t)bt * Nn + n0) * Aa + a;
  float acc = 0.f;
  for (int i = 0; i < 14; ++i) {
    size_t o = base + (size_t)i * Aa;
    short pos = posmap[bt * Nn + n0 + i];
    float am = pos ? attln[(((size_t)(b * KK + pos - 1) * Tt) + t) * Aa + a]
                   : ab;
    float f = g0 * bf2f(local[o]) + g1 * bf2f(trans[o]) + g2 * am;
    fused[o] = f2bf(f);
    acc += f;
  }
  fpart[(size_t)blk * Aa + a] = acc;
}

// cls_out: fpart NCH partials
__global__ void cls_kernel(const float* __restrict__ fpart,
                           const float* __restrict__ cw,
                           const float* __restrict__ cb,
                           const float* __restrict__ x,
                           float* __restrict__ out) {
  int bt = blockIdx.x;
  __shared__ float fm[Aa];
  int tid = threadIdx.x;
  if (tid < Aa) {
    float s = 0.f;
    for (int ch = 0; ch < NCH; ++ch)
      s += fpart[(size_t)(bt * NCH + ch) * Aa + tid];
    fm[tid] = s * (1.0f / 196.0f);
  }
  __syncthreads();
  for (int c = tid; c < Cc; c += 256) {
    const float* w = cw + (size_t)c * Aa;
    float s = cb[c];
#pragma unroll 8
    for (int a = 0; a < Aa; ++a) s = fmaf(fm[a], w[a], s);
    size_t off = (size_t)bt * (Nn + 1) * Cc + c;
    out[off] = x[off] + s;
  }
}

// ============================================================
extern "C" void kernel_launch(void* const* d_in, const int* in_sizes, int n_in,
                              void* d_out, int out_size, void* d_ws,
                              size_t ws_size, hipStream_t stream) {
  const float* x = (const float*)d_in[0];
  const float* down_w = (const float*)d_in[1];
  const float* down_b = (const float*)d_in[2];
  const float* ldw_w = (const float*)d_in[3];
  const float* lpw_w = (const float*)d_in[4];
  const float* lnorm_g = (const float*)d_in[5];
  const float* lnorm_b = (const float*)d_in[6];
  const float* tdw_w = (const float*)d_in[7];
  const float* tpw_w = (const float*)d_in[8];
  const float* tmlp_w1 = (const float*)d_in[9];
  const float* tmlp_b1 = (const float*)d_in[10];
  const float* tmlp_w2 = (const float*)d_in[11];
  const float* tmlp_b2 = (const float*)d_in[12];
  const float* tnorm_g = (const float*)d_in[13];
  const float* tnorm_b = (const float*)d_in[14];
  const float* attn_in_w = (const float*)d_in[15];
  const float* attn_in_b = (const float*)d_in[16];
  const float* attn_out_w = (const float*)d_in[17];
  const float* attn_out_b = (const float*)d_in[18];
  const float* aproj_w = (const float*)d_in[19];
  const float* aproj_b = (const float*)d_in[20];
  const float* anorm_g = (const float*)d_in[21];
  const float* anorm_b = (const float*)d_in[22];
  const float* gate_w1 = (const float*)d_in[23];
  const float* gate_b1 = (const float*)d_in[24];
  const float* gate_w2 = (const float*)d_in[25];
  const float* gate_b2 = (const float*)d_in[26];
  const float* up_w = (const float*)d_in[27];
  const float* up_b = (const float*)d_in[28];
  const float* cls_w = (const float*)d_in[29];
  const float* cls_b = (const float*)d_in[30];
  float* out = (float*)d_out;

  float* ws = (float*)d_ws;
  float* W0 = ws;              // ph bf16 -> trp bf16
  float* W1 = W0 + SZ;         // delta bf16 -> transition bf16
  float* W2 = W1 + SZ;         // attn scratch -> locg/trg/h1/fused bf16
  float* W3 = W2 + 2 * SZ;     // local bf16
  float* sal = W3 + SZ;
  float* attout = sal + BTN;
  float* dppart2 = attout + (size_t)BKT * Aa;          // BT*NCH*Aa
  float* appart = dppart2 + (size_t)BT * NCH * Aa;
  float* gw = appart + (size_t)Bb * KK * Aa;
  float* fpart = gw + (size_t)Bb * 3 * Aa;             // BT*NCH*Aa
  double* sal64 = (double*)(fpart + (size_t)BT * NCH * Aa);
  int* cand = (int*)(sal64 + (size_t)BT * NCAND);
  int* idx = cand + (size_t)BT * NCAND;
  float* wT = (float*)(idx + (size_t)BT * KK);
  short* posmap = (short*)(wT + (size_t)Cc * Aa);
  ushortt* wbuf = (ushortt*)(posmap + (size_t)BT * Nn);

  // bf16 weight views
  ushortt* wb_down   = wbuf;
  ushortt* wb_attnin = wbuf + O1;
  ushortt* wb_attnout= wbuf + O2;
  ushortt* wb_aproj  = wbuf + O3;
  ushortt* wb_lpw    = wbuf + O4;
  ushortt* wb_tpw    = wbuf + O5;
  ushortt* wb_t1     = wbuf + O6;
  ushortt* wb_t2     = wbuf + O7;
  ushortt* wb_up     = wbuf + O8;

  // bf16 activation views
  ushortt* ph_b    = (ushortt*)W0;
  ushortt* trp_b   = (ushortt*)W0;
  ushortt* delta_b = (ushortt*)W1;
  ushortt* trans_b = (ushortt*)W1;
  ushortt* locg_b  = (ushortt*)W2;
  ushortt* trg_b   = (ushortt*)W2;
  ushortt* h1_b    = (ushortt*)W2;
  ushortt* fused_b = (ushortt*)W2;
  ushortt* local_b = (ushortt*)W3;

  // attn-phase scratch inside W2 (dead until conv2d)
  ushortt* tok_b = (ushortt*)W2;
  float* qkvb  = W2 + (size_t)BKT * Aa / 2;
  float* obuf  = qkvb + (size_t)BKT * 3 * Aa;
  float* proj1 = obuf + (size_t)BKT * Aa;

  // 0. weights -> bf16, wT for refine
  cvtw_kernel<<<OTOT / 256, 256, 0, stream>>>(
      down_w, attn_in_w, attn_out_w, aproj_w, lpw_w, tpw_w, tmlp_w1,
      tmlp_w2, up_w, wbuf);
  transpose_w<<<(Cc * Aa) / 256, 256, 0, stream>>>(down_w, wT);
  // 1. ph = patch @ down_w.T + down_b (hybrid, K=768)
  gemm_hyb<1, ushortt, 1, 0><<<dim3(2, 784), 256, 0, stream>>>(
      x, wb_down, down_b, ph_b, nullptr, BTN, Aa, Cc);
  // 2+3a. delta + dp partials + sal (fused, 14-way parallel)
  delta14_kernel<<<BT * NCH, 192, 0, stream>>>(ph_b, delta_b, dppart2, sal);
  // 3b. candidates -> f64 refine -> exact top-8
  topcand_kernel<<<BT, 64, 0, stream>>>(sal, cand);
  refine_kernel<<<dim3(BT, 2), 192, 0, stream>>>(x, wT, cand, sal64);
  select_kernel<<<BT, 64, 0, stream>>>(sal64, cand, idx);
  // 4. anchor attention (qkv K=192 -> single-step)
  gather_kernel<<<BKT, Aa, 0, stream>>>(ph_b, delta_b, idx, tok_b);
  gemm_k192<float, 1, 0><<<dim3(6, 32), 256, 0, stream>>>(
      tok_b, wb_attnin, attn_in_b, qkvb, nullptr, BKT, 3 * Aa);
  attn_core<<<Bb * KK, 256, 0, stream>>>(qkvb, obuf);
  gemm_hyb<0, float, 1, 0><<<dim3(2, 32), 256, 0, stream>>>(
      obuf, wb_attnout, attn_out_b, proj1, nullptr, BKT, Aa, Aa);
  gemm_hyb<0, float, 1, 0><<<dim3(2, 32), 256, 0, stream>>>(
      proj1, wb_aproj, aproj_b, attout, nullptr, BKT, Aa, Aa);
  appart_kernel<<<Bb * KK, Aa, 0, stream>>>(attout, appart);
  // 4b. LN the 2048 anchor rows in place
  ln32_kernel<<<BKT / 4, 256, 0, stream>>>(attout, anorm_g, anorm_b);
  hipMemsetAsync(posmap, 0, (size_t)BT * Nn * sizeof(short), stream);
  scatter_pos<<<BT, 64, 0, stream>>>(idx, posmap);
  // 5. local branch (lpw K=192 -> single-step)
  conv2d_kernel<<<(unsigned)(SZ / 256), 256, 0, stream>>>(ph_b, ldw_w, locg_b);
  gemm_k192<ushortt, 0, 0><<<dim3(2, 784), 256, 0, stream>>>(
      locg_b, wb_lpw, nullptr, local_b, nullptr, BTN, Aa);
  ln_kernel<<<BTN / 4, 256, 0, stream>>>(local_b, lnorm_g, lnorm_b);
  // 6. transition branch (tpw/tmlp1 K=192 -> single-step)
  conv1d_kernel<<<(unsigned)(SZ / 256), 256, 0, stream>>>(delta_b, tdw_w, trg_b);
  gemm_k192<ushortt, 0, 0><<<dim3(2, 784), 256, 0, stream>>>(
      trg_b, wb_tpw, nullptr, trp_b, nullptr, BTN, Aa);
  gemm_k192<ushortt, 1, 1><<<dim3(4, 784), 256, 0, stream>>>(
      trp_b, wb_t1, tmlp_b1, h1_b, nullptr, BTN, 2 * Aa);
  gemm_lds<ushortt, 1, 0><<<dim3(2, 784), 256, 0, stream>>>(
      h1_b, wb_t2, tmlp_b2, trans_b, nullptr, BTN, Aa, 2 * Aa);
  ln_kernel<<<BTN / 4, 256, 0, stream>>>(trans_b, tnorm_g, tnorm_b);
  // 8. gate
  gate_kernel<<<Bb, Aa, 0, stream>>>(dppart2, appart, gate_w1, gate_b1,
                                     gate_w2, gate_b2, gw);
  // 9. fuse (14-way parallel) + output projections (up K=192 -> single-step)
  fused14_kernel<<<BT * NCH, 192, 0, stream>>>(local_b, trans_b, attout,
                                               posmap, anorm_b, gw, fused_b,
                                               fpart);
  gemm_k192<float, 1, 2><<<dim3(8, 784), 256, 0, stream>>>(
      fused_b, wb_up, up_b, out, x, BTN, Cc);
  cls_kernel<<<BT, 256, 0, stream>>>(fpart, cls_w, cls_b, x, out);
}

// Round 21
// 528.035 us; speedup vs baseline: 1.0241x; 1.0241x over previous
//
#include <hip/hip_runtime.h>
#include <hip/hip_bf16.h>
#include <math.h>

// ---- fixed problem dims ----
constexpr int Bb  = 16;
constexpr int Tt  = 16;
constexpr int Nn  = 196;   // patches (14x14)
constexpr int Cc  = 768;
constexpr int Aa  = 192;
constexpr int KK  = 8;     // TOPK
constexpr int NCAND = 16;  // fp32 candidates refined in f64
constexpr int NCH = 14;    // n-chunks for delta/fused parallelism
constexpr int BT  = Bb * Tt;            // 256
constexpr int BTN = BT * Nn;            // 50176
constexpr int BKT = Bb * KK * Tt;       // 2048 anchor-token rows
constexpr size_t SZ = (size_t)BTN * Aa; // 9,633,792 floats

typedef unsigned short ushortt;
typedef __attribute__((ext_vector_type(8))) short bf16x8;
typedef __attribute__((ext_vector_type(4))) float f32x4;
typedef __attribute__((ext_vector_type(4))) unsigned short u16x4;
typedef __attribute__((ext_vector_type(8))) unsigned short u16x8;

static __device__ __forceinline__ float gelu_f(float x) {
  return 0.5f * x * (1.0f + erff(x * 0.7071067811865476f));
}
static __device__ __forceinline__ ushortt f2bf(float f) {
  __hip_bfloat16 h = __float2bfloat16(f);
  return *reinterpret_cast<ushortt*>(&h);
}
static __device__ __forceinline__ float bf2f(ushortt u) {
  return __uint_as_float(((unsigned)u) << 16);
}
static __device__ __forceinline__ void gload16(const void* g, void* l) {
  __builtin_amdgcn_global_load_lds(
      (const __attribute__((address_space(1))) void*)g,
      (__attribute__((address_space(3))) void*)l, 16, 0, 0);
}

// ---- weight pre-convert offsets ----
constexpr int S_down   = Aa * Cc;
constexpr int S_attnin = 3 * Aa * Aa;
constexpr int S_sq     = Aa * Aa;
constexpr int S_t      = 2 * Aa * Aa;
constexpr int O1 = S_down;
constexpr int O2 = O1 + S_attnin;
constexpr int O3 = O2 + S_sq;
constexpr int O4 = O3 + S_sq;
constexpr int O5 = O4 + S_sq;
constexpr int O6 = O5 + S_sq;
constexpr int O7 = O6 + S_t;
constexpr int O8 = O7 + S_t;
constexpr int OTOT = O8 + S_down;  // 700416

__global__ void cvtw_kernel(const float* __restrict__ w0,
                            const float* __restrict__ w1,
                            const float* __restrict__ w2,
                            const float* __restrict__ w3,
                            const float* __restrict__ w4,
                            const float* __restrict__ w5,
                            const float* __restrict__ w6,
                            const float* __restrict__ w7,
                            const float* __restrict__ w8,
                            ushortt* __restrict__ outw) {
  int e = blockIdx.x * 256 + threadIdx.x;
  const float* src;
  int off;
  if (e < O1)      { src = w0; off = 0;  }
  else if (e < O2) { src = w1; off = O1; }
  else if (e < O3) { src = w2; off = O2; }
  else if (e < O4) { src = w3; off = O3; }
  else if (e < O5) { src = w4; off = O4; }
  else if (e < O6) { src = w5; off = O5; }
  else if (e < O7) { src = w6; off = O6; }
  else if (e < O8) { src = w7; off = O7; }
  else             { src = w8; off = O8; }
  outw[e] = f2bf(src[e - off]);
}

// ============================================================
// gemm_lds (r15): bf16 A & W via global_load_lds, XOR swizzle.
// ============================================================
template <typename CT, int BIAS, int EPI>
__global__ __launch_bounds__(256) void gemm_lds(
    const ushortt* __restrict__ Ain, const ushortt* __restrict__ Wb,
    const float* __restrict__ bias, CT* __restrict__ Cout,
    const float* __restrict__ resid, int M, int Nc, int K) {
  __shared__ __align__(16) unsigned char smem[40960];
  ushortt (*As)[64 * 64] = (ushortt(*)[64 * 64])smem;
  ushortt (*Bs)[96 * 64] = (ushortt(*)[96 * 64])(smem + 2 * 64 * 64 * 2);
  const int tid = threadIdx.x;

  const int ncb = gridDim.x;
  const int nwg = ncb * gridDim.y;
  const int bid = blockIdx.y * ncb + blockIdx.x;
  const int cpx = nwg >> 3;
  const int swz = (bid & 7) * cpx + (bid >> 3);
  const int row0 = (swz / ncb) * 64;
  const int col0 = (swz % ncb) * 96;

  const int wid = tid >> 6;
  const int lane = tid & 63;
  const int wr = wid >> 1;
  const int wc = wid & 1;
  const int l15 = lane & 15;
  const int kgrp = lane >> 4;

  const int lr = lane >> 3;
  const int lc = 8 * ((lane & 7) ^ lr);

  f32x4 acc[2][3];
#pragma unroll
  for (int i = 0; i < 2; ++i)
#pragma unroll
    for (int j = 0; j < 3; ++j) acc[i][j] = (f32x4){0.f, 0.f, 0.f, 0.f};

#define ISSUE(buf, k0)                                                       \
  do {                                                                       \
    _Pragma("unroll") for (int i = 0; i < 2; ++i) {                          \
      int j = 2 * wid + i;                                                   \
      const ushortt* g =                                                     \
          Ain + (size_t)(row0 + 8 * j + lr) * K + (k0) + lc;                 \
      gload16(g, &As[buf][j * 512]);                                         \
    }                                                                        \
    _Pragma("unroll") for (int i = 0; i < 3; ++i) {                          \
      int j = 3 * wid + i;                                                   \
      const ushortt* g =                                                     \
          Wb + (size_t)(col0 + 8 * j + lr) * K + (k0) + lc;                  \
      gload16(g, &Bs[buf][j * 512]);                                         \
    }                                                                        \
  } while (0)

  ISSUE(0, 0);
  __syncthreads();

  const int nsteps = K >> 6;
  int cur = 0;
  for (int step = 0; step < nsteps; ++step) {
    const bool pref = (step + 1 < nsteps);
    if (pref) ISSUE(cur ^ 1, (step + 1) << 6);
#pragma unroll
    for (int kk = 0; kk < 2; ++kk) {
      const int cb = kk * 64 + kgrp * 16;
      bf16x8 af[2], bfv[3];
#pragma unroll
      for (int fm = 0; fm < 2; ++fm) {
        int r = wr * 32 + fm * 16 + l15;
        af[fm] = *(const bf16x8*)&As[cur][r * 64 +
                                          ((cb ^ ((r & 7) << 4)) >> 1)];
      }
#pragma unroll
      for (int fn = 0; fn < 3; ++fn) {
        int r = wc * 48 + fn * 16 + l15;
        bfv[fn] = *(const bf16x8*)&Bs[cur][r * 64 +
                                           ((cb ^ ((r & 7) << 4)) >> 1)];
      }
#pragma unroll
      for (int fm = 0; fm < 2; ++fm)
#pragma unroll
        for (int fn = 0; fn < 3; ++fn)
          acc[fm][fn] = __builtin_amdgcn_mfma_f32_16x16x32_bf16(
              af[fm], bfv[fn], acc[fm][fn], 0, 0, 0);
    }
    __syncthreads();
    cur ^= 1;
  }
#undef ISSUE

  constexpr int EP = 100;
  float* epi = (float*)smem;
#pragma unroll
  for (int fm = 0; fm < 2; ++fm) {
    int rl = wr * 32 + fm * 16 + kgrp * 4;
#pragma unroll
    for (int fn = 0; fn < 3; ++fn) {
      int cl = wc * 48 + fn * 16 + l15;
#pragma unroll
      for (int j = 0; j < 4; ++j)
        epi[(rl + j) * EP + cl] = acc[fm][fn][j];
    }
  }
  __syncthreads();
#pragma unroll
  for (int it = 0; it < 6; ++it) {
    int f = it * 256 + tid;
    int r = f / 24, c4 = f - r * 24;
    float4 v = *(const float4*)&epi[r * EP + c4 * 4];
    int c = col0 + c4 * 4;
    if (BIAS) {
      float4 bv = *(const float4*)(bias + c);
      v.x += bv.x; v.y += bv.y; v.z += bv.z; v.w += bv.w;
    }
    if (EPI == 1) {
      v.x = gelu_f(v.x); v.y = gelu_f(v.y);
      v.z = gelu_f(v.z); v.w = gelu_f(v.w);
    }
    int R = row0 + r;
    if constexpr (EPI == 2) {
      int bt2 = R / Nn, n2 = R - bt2 * Nn;
      size_t off = (size_t)(bt2 * (Nn + 1) + 1 + n2) * Nc + c;
      float4 rv = *(const float4*)(resid + off);
      v.x += rv.x; v.y += rv.y; v.z += rv.z; v.w += rv.w;
      *(float4*)((float*)Cout + off) = v;
    } else if constexpr (sizeof(CT) == 4) {
      *(float4*)((float*)Cout + (size_t)R * Nc + c) = v;
    } else {
      u16x4 ob = {f2bf(v.x), f2bf(v.y), f2bf(v.z), f2bf(v.w)};
      *(u16x4*)((ushortt*)Cout + (size_t)R * Nc + c) = ob;
    }
  }
}

// ============================================================
// gemm_hyb (r16): fp32 A reg-staged (pitched), bf16 W via gload.
// ============================================================
template <int ROWMAP, typename CT, int BIAS, int EPI>
__global__ __launch_bounds__(256) void gemm_hyb(
    const float* __restrict__ Ain, const ushortt* __restrict__ Wb,
    const float* __restrict__ bias, CT* __restrict__ Cout,
    const float* __restrict__ resid, int M, int Nc, int K) {
  constexpr int PIT = 72;
  __shared__ __align__(16) unsigned char smem[43008];
  ushortt (*As)[64 * PIT] = (ushortt(*)[64 * PIT])smem;
  ushortt (*Bs)[96 * 64] = (ushortt(*)[96 * 64])(smem + 18432);
  const int tid = threadIdx.x;

  const int ncb = gridDim.x;
  const int nwg = ncb * gridDim.y;
  const int bid = blockIdx.y * ncb + blockIdx.x;
  const int cpx = nwg >> 3;
  const int swz = (bid & 7) * cpx + (bid >> 3);
  const int row0 = (swz / ncb) * 64;
  const int col0 = (swz % ncb) * 96;

  const int wid = tid >> 6;
  const int lane = tid & 63;
  const int wr = wid >> 1;
  const int wc = wid & 1;
  const int l15 = lane & 15;
  const int kgrp = lane >> 4;

  const int q16 = tid & 15;
  const int lr = lane >> 3;
  const int lc = 8 * ((lane & 7) ^ lr);

  const int nsteps = K >> 6;

  const float* arowf[4];
#pragma unroll
  for (int p = 0; p < 4; ++p) {
    int r = row0 + (tid >> 4) + 16 * p;
    if (ROWMAP) {
      int bt = r / Nn;
      int n = r - bt * Nn;
      arowf[p] = Ain + (size_t)(bt * (Nn + 1) + 1 + n) * K;
    } else {
      arowf[p] = Ain + (size_t)r * K;
    }
  }

  f32x4 acc[2][3];
#pragma unroll
  for (int i = 0; i < 2; ++i)
#pragma unroll
    for (int j = 0; j < 3; ++j) acc[i][j] = (f32x4){0.f, 0.f, 0.f, 0.f};

  float4 apre[4];

#define ISSUE_B(buf, k0)                                                     \
  do {                                                                       \
    _Pragma("unroll") for (int i = 0; i < 3; ++i) {                          \
      int j = 3 * wid + i;                                                   \
      const ushortt* g =                                                     \
          Wb + (size_t)(col0 + 8 * j + lr) * K + (k0) + lc;                  \
      gload16(g, &Bs[buf][j * 512]);                                         \
    }                                                                        \
  } while (0)

#define STAGE_LOAD_A(k0)                                                     \
  _Pragma("unroll") for (int p = 0; p < 4; ++p)                              \
      apre[p] = *(const float4*)(arowf[p] + (k0) + q16 * 4);

#define STAGE_WRITE_A(buf)                                                   \
  _Pragma("unroll") for (int p = 0; p < 4; ++p) {                            \
    u16x4 b = {f2bf(apre[p].x), f2bf(apre[p].y), f2bf(apre[p].z),            \
               f2bf(apre[p].w)};                                             \
    *(u16x4*)&As[buf][((tid >> 4) + 16 * p) * PIT + q16 * 4] = b;            \
  }

  ISSUE_B(0, 0);
  STAGE_LOAD_A(0);
  STAGE_WRITE_A(0);
  __syncthreads();

  int cur = 0;
  for (int step = 0; step < nsteps; ++step) {
    const bool pref = (step + 1 < nsteps);
    if (pref) {
      int k0 = (step + 1) << 6;
      ISSUE_B(cur ^ 1, k0);
      STAGE_LOAD_A(k0);
    }
#pragma unroll
    for (int kk = 0; kk < 2; ++kk) {
      const int cb = kk * 64 + kgrp * 16;
      bf16x8 af[2], bfv[3];
#pragma unroll
      for (int fm = 0; fm < 2; ++fm)
        af[fm] = *(const bf16x8*)&As[cur][(wr * 32 + fm * 16 + l15) * PIT +
                                          kk * 32 + kgrp * 8];
#pragma unroll
      for (int fn = 0; fn < 3; ++fn) {
        int r = wc * 48 + fn * 16 + l15;
        bfv[fn] = *(const bf16x8*)&Bs[cur][r * 64 +
                                           ((cb ^ ((r & 7) << 4)) >> 1)];
      }
#pragma unroll
      for (int fm = 0; fm < 2; ++fm)
#pragma unroll
        for (int fn = 0; fn < 3; ++fn)
          acc[fm][fn] = __builtin_amdgcn_mfma_f32_16x16x32_bf16(
              af[fm], bfv[fn], acc[fm][fn], 0, 0, 0);
    }
    if (pref) {
      STAGE_WRITE_A(cur ^ 1);
    }
    __syncthreads();
    cur ^= 1;
  }
#undef ISSUE_B
#undef STAGE_LOAD_A
#undef STAGE_WRITE_A

  constexpr int EP = 100;
  float* epi = (float*)smem;
#pragma unroll
  for (int fm = 0; fm < 2; ++fm) {
    int rl = wr * 32 + fm * 16 + kgrp * 4;
#pragma unroll
    for (int fn = 0; fn < 3; ++fn) {
      int cl = wc * 48 + fn * 16 + l15;
#pragma unroll
      for (int j = 0; j < 4; ++j)
        epi[(rl + j) * EP + cl] = acc[fm][fn][j];
    }
  }
  __syncthreads();
#pragma unroll
  for (int it = 0; it < 6; ++it) {
    int f = it * 256 + tid;
    int r = f / 24, c4 = f - r * 24;
    float4 v = *(const float4*)&epi[r * EP + c4 * 4];
    int c = col0 + c4 * 4;
    if (BIAS) {
      float4 bv = *(const float4*)(bias + c);
      v.x += bv.x; v.y += bv.y; v.z += bv.z; v.w += bv.w;
    }
    if (EPI == 1) {
      v.x = gelu_f(v.x); v.y = gelu_f(v.y);
      v.z = gelu_f(v.z); v.w = gelu_f(v.w);
    }
    int R = row0 + r;
    if constexpr (EPI == 2) {
      int bt2 = R / Nn, n2 = R - bt2 * Nn;
      size_t off = (size_t)(bt2 * (Nn + 1) + 1 + n2) * Nc + c;
      float4 rv = *(const float4*)(resid + off);
      v.x += rv.x; v.y += rv.y; v.z += rv.z; v.w += rv.w;
      *(float4*)((float*)Cout + off) = v;
    } else if constexpr (sizeof(CT) == 4) {
      *(float4*)((float*)Cout + (size_t)R * Nc + c) = v;
    } else {
      u16x4 ob = {f2bf(v.x), f2bf(v.y), f2bf(v.z), f2bf(v.w)};
      *(u16x4*)((ushortt*)Cout + (size_t)R * Nc + c) = ob;
    }
  }
}

// ============================================================
// delta14 (r17)
// ============================================================
__global__ __launch_bounds__(192) void delta14_kernel(
    const ushortt* __restrict__ ph, ushortt* __restrict__ delta,
    float* __restrict__ dppart2, float* __restrict__ sal) {
  int blk = blockIdx.x;
  int bt = blk / NCH, chunk = blk - bt * NCH;
  int t = bt & 15;
  int a = threadIdx.x;
  int n0 = chunk * 14;
  __shared__ float spart[3][14];
  const ushortt* cur = ph + ((size_t)bt * Nn + n0) * Aa + a;
  ushortt* dl = delta + ((size_t)bt * Nn + n0) * Aa + a;
  int wv = a >> 6, ln = a & 63;
  float acc = 0.f;
  if (t == 0) {
    for (int i = 0; i < 14; ++i) dl[(size_t)i * Aa] = 0;
    if (a < 14) sal[(size_t)bt * Nn + n0 + a] = 0.f;
    dppart2[(size_t)blk * Aa + a] = 0.f;
    return;
  }
  const ushortt* prev = cur - (size_t)Nn * Aa;
  for (int i = 0; i < 14; ++i) {
    float d = bf2f(cur[(size_t)i * Aa]) - bf2f(prev[(size_t)i * Aa]);
    dl[(size_t)i * Aa] = f2bf(d);
    float ad = fabsf(d);
    acc += ad;
    float s = ad;
#pragma unroll
    for (int off = 32; off > 0; off >>= 1) s += __shfl_xor(s, off, 64);
    if (ln == 0) spart[wv][i] = s;
  }
  dppart2[(size_t)blk * Aa + a] = acc;
  __syncthreads();
  if (a < 14)
    sal[(size_t)bt * Nn + n0 + a] =
        (spart[0][a] + spart[1][a] + spart[2][a]) * (1.0f / 192.0f);
}

// ============================================================
// top-16 fp32 candidates per (b,t)
// ============================================================
__global__ void topcand_kernel(const float* __restrict__ sal,
                               int* __restrict__ cand) {
  int bt = blockIdx.x;
  int lane = threadIdx.x;
  unsigned long long key[4];
#pragma unroll
  for (int j = 0; j < 4; ++j) {
    int n = lane + 64 * j;
    if (n < Nn) {
      unsigned fb = __float_as_uint(sal[(size_t)bt * Nn + n]);
      key[j] = ((unsigned long long)fb << 32) |
               (unsigned long long)(0xFFFFFFFFu - (unsigned)n);
    } else {
      key[j] = 0ULL;
    }
  }
  for (int r = 0; r < NCAND; ++r) {
    unsigned long long m = key[0];
    if (key[1] > m) m = key[1];
    if (key[2] > m) m = key[2];
    if (key[3] > m) m = key[3];
#pragma unroll
    for (int off = 32; off > 0; off >>= 1) {
      unsigned long long o = __shfl_xor(m, off, 64);
      if (o > m) m = o;
    }
    if (lane == 0)
      cand[bt * NCAND + r] = (int)(0xFFFFFFFFu - (unsigned)(m & 0xFFFFFFFFull));
#pragma unroll
    for (int j = 0; j < 4; ++j)
      if (key[j] == m) key[j] = 0ULL;
  }
}

// one-time transpose: wT[c][a] = down_w[a][c]
__global__ void transpose_w(const float* __restrict__ w,
                            float* __restrict__ wT) {
  int e = blockIdx.x * 256 + threadIdx.x;
  int c = e / Aa, a = e - c * Aa;
  wT[e] = w[(size_t)a * Cc + c];
}

// ============================================================
// f64 refine (r7)
// ============================================================
__global__ __launch_bounds__(192) void refine_kernel(
    const float* __restrict__ x, const float* __restrict__ wT,
    const int* __restrict__ cand, double* __restrict__ sal64) {
  int bt = blockIdx.x;
  int grp = blockIdx.y;
  int t = bt & 15;
  int a = threadIdx.x;
  if (t == 0) {
    if (a < 8) sal64[bt * NCAND + grp * 8 + a] = 0.0;
    return;
  }
  __shared__ double sdiff[8][Cc];
  const float* xt = x + ((size_t)bt * (Nn + 1) + 1) * Cc;
  const float* xp = xt - (size_t)(Nn + 1) * Cc;
  for (int g = 0; g < 8; ++g) {
    int n = cand[bt * NCAND + grp * 8 + g];
    const float* rt = xt + (size_t)n * Cc;
    const float* rp = xp + (size_t)n * Cc;
    for (int c = a; c < Cc; c += 192)
      sdiff[g][c] = (double)rt[c] - (double)rp[c];
  }
  __syncthreads();
  double acc[8] = {};
  for (int c = 0; c < Cc; ++c) {
    double wv = (double)wT[(size_t)c * Aa + a];
#pragma unroll
    for (int g = 0; g < 8; ++g) acc[g] = fma(wv, sdiff[g][c], acc[g]);
  }
  __shared__ double part[3][8];
  int wvx = a >> 6, ln = a & 63;
#pragma unroll
  for (int g = 0; g < 8; ++g) {
    double v = fabs(acc[g]);
#pragma unroll
    for (int off = 32; off > 0; off >>= 1) v += __shfl_xor(v, off, 64);
    if (ln == 0) part[wvx][g] = v;
  }
  __syncthreads();
  if (a < 8) {
    double s = part[0][a] + part[1][a] + part[2][a];
    sal64[bt * NCAND + grp * 8 + a] = s * (1.0 / 192.0);
  }
}

// final top-8 (r14 wave-parallel)
__global__ void select_kernel(const double* __restrict__ sal64,
                              const int* __restrict__ cand,
                              int* __restrict__ idx) {
  int bt = blockIdx.x;
  int t = bt & 15;
  int lane = threadIdx.x;
  if (t == 0) {
    if (lane < KK) idx[bt * KK + lane] = lane;
    return;
  }
  double v = (lane < NCAND) ? sal64[bt * NCAND + lane] : -1.0;
  int n = (lane < NCAND) ? cand[bt * NCAND + lane] : 0x7FFFFFFF;
  for (int r = 0; r < KK; ++r) {
    double bv = v;
    int bn = n, bl = lane;
#pragma unroll
    for (int off = 8; off >= 1; off >>= 1) {
      double ov = __shfl_xor(bv, off, 64);
      int on = __shfl_xor(bn, off, 64);
      int ol = __shfl_xor(bl, off, 64);
      if (ov > bv || (ov == bv && on < bn)) { bv = ov; bn = on; bl = ol; }
    }
    if (lane == 0) idx[bt * KK + r] = bn;
    if (lane == bl) v = -1.0;
  }
}

// ============================================================
// anchor attention pieces
// ============================================================
__global__ void gather_kernel(const ushortt* __restrict__ ph,
                              const ushortt* __restrict__ delta,
                              const int* __restrict__ idx,
                              ushortt* __restrict__ tok) {
  int row = blockIdx.x;
  int t = row & 15;
  int bk = row >> 4;
  int b = bk >> 3, k = bk & 7;
  int a = threadIdx.x;
  int n = idx[(b * 16 + t) * KK + k];
  size_t off = ((size_t)(b * 16 + t) * Nn + n) * Aa + a;
  tok[(size_t)row * Aa + a] = f2bf(bf2f(ph[off]) + bf2f(delta[off]));
}

__global__ __launch_bounds__(256) void attn_core(
    const float* __restrict__ qkv, float* __restrict__ o) {
  constexpr int P = 580;
  __shared__ float sq[16 * P];
  __shared__ float ssc[4][16][17];
  int bk = blockIdx.x;
  int tid = threadIdx.x;
  const float* src = qkv + (size_t)bk * 16 * 576;
  for (int e = tid; e < 16 * 144; e += 256) {
    int r = e / 144, c4 = e % 144;
    float4 v = *(const float4*)(src + r * 576 + c4 * 4);
    *(float4*)(&sq[r * P + c4 * 4]) = v;
  }
  __syncthreads();
  int h = tid >> 6, lane = tid & 63;
#pragma unroll
  for (int s4 = 0; s4 < 4; ++s4) {
    int e = lane + 64 * s4;
    int i = e >> 4, j = e & 15;
    const float* q = sq + i * P + h * 48;
    const float* k2 = sq + j * P + 192 + h * 48;
    float s = 0.f;
#pragma unroll
    for (int d = 0; d < 48; ++d) s = fmaf(q[d], k2[d], s);
    ssc[h][i][j] = s * 0.14433756729740643f;
  }
  __syncthreads();
  if (lane < 16) {
    float* r = ssc[h][lane];
    float mx = r[0];
    for (int j = 1; j < 16; ++j) mx = fmaxf(mx, r[j]);
    float sum = 0.f;
    for (int j = 0; j < 16; ++j) {
      float ev = expf(r[j] - mx);
      r[j] = ev;
      sum += ev;
    }
    float inv = 1.0f / sum;
    for (int j = 0; j < 16; ++j) r[j] *= inv;
  }
  __syncthreads();
#pragma unroll
  for (int s4 = 0; s4 < 12; ++s4) {
    int e = lane + 64 * s4;
    int i = e / 48, d = e - i * 48;
    float s = 0.f;
#pragma unroll
    for (int j = 0; j < 16; ++j)
      s = fmaf(ssc[h][i][j], sq[j * P + 384 + h * 48 + d], s);
    o[((size_t)bk * 16 + i) * 192 + h * 48 + d] = s;
  }
}

__global__ void appart_kernel(const float* __restrict__ attout,
                              float* __restrict__ appart) {
  int bk = blockIdx.x;
  int a = threadIdx.x;
  float s = 0.f;
  for (int t = 0; t < Tt; ++t)
    s += attout[((size_t)bk * Tt + t) * Aa + a];
  appart[bk * Aa + a] = s;
}

__global__ void ln32_kernel(float* __restrict__ buf,
                            const float* __restrict__ g,
                            const float* __restrict__ bb) {
  size_t row = (size_t)blockIdx.x * 4 + (threadIdx.x >> 6);
  int lane = threadIdx.x & 63;
  float* p = buf + row * Aa;
  float v0 = p[lane], v1 = p[lane + 64], v2 = p[lane + 128];
  float s = v0 + v1 + v2;
#pragma unroll
  for (int off = 32; off > 0; off >>= 1) s += __shfl_xor(s, off, 64);
  float m = s * (1.0f / 192.0f);
  float d0 = v0 - m, d1 = v1 - m, d2 = v2 - m;
  float ss = d0 * d0 + d1 * d1 + d2 * d2;
#pragma unroll
  for (int off = 32; off > 0; off >>= 1) ss += __shfl_xor(ss, off, 64);
  float inv = rsqrtf(ss * (1.0f / 192.0f) + 1e-5f);
  p[lane] = d0 * inv * g[lane] + bb[lane];
  p[lane + 64] = d1 * inv * g[lane + 64] + bb[lane + 64];
  p[lane + 128] = d2 * inv * g[lane + 128] + bb[lane + 128];
}

// depthwise 3x3 SAME conv + gelu; bf16
__global__ void conv2d_kernel(const ushortt* __restrict__ ph,
                              const float* __restrict__ ldw,
                              ushortt* __restrict__ og) {
  size_t e = (size_t)blockIdx.x * 256 + threadIdx.x;
  int a = (int)(e % Aa);
  size_t r = e / Aa;
  int n = (int)(r % Nn);
  int bt = (int)(r / Nn);
  int y = n / 14, x = n % 14;
  const ushortt* base = ph + (size_t)bt * Nn * Aa + a;
  const float* w = ldw + a * 9;
  float s = 0.f;
#pragma unroll
  for (int dy = -1; dy <= 1; ++dy) {
    int yy = y + dy;
    if (yy < 0 || yy >= 14) continue;
#pragma unroll
    for (int dx = -1; dx <= 1; ++dx) {
      int xc = x + dx;
      if (xc < 0 || xc >= 14) continue;
      s = fmaf(bf2f(base[(size_t)(yy * 14 + xc) * Aa]),
               w[(dy + 1) * 3 + (dx + 1)], s);
    }
  }
  og[e] = f2bf(gelu_f(s));
}

// depthwise k=3 conv over t + gelu; bf16
__global__ void conv1d_kernel(const ushortt* __restrict__ delta,
                              const float* __restrict__ tdw,
                              ushortt* __restrict__ og) {
  size_t e = (size_t)blockIdx.x * 256 + threadIdx.x;
  int a = (int)(e % Aa);
  size_t r = e / Aa;
  int n = (int)(r % Nn);
  int bt = (int)(r / Nn);
  int t = bt & 15, b = bt >> 4;
  const float* w = tdw + a * 3;
  float s = 0.f;
#pragma unroll
  for (int j = 0; j < 3; ++j) {
    int tt = t + j - 1;
    if (tt >= 0 && tt < Tt)
      s = fmaf(bf2f(delta[((size_t)(b * Tt + tt) * Nn + n) * Aa + a]), w[j], s);
  }
  og[e] = f2bf(gelu_f(s));
}

// in-place bf16 LayerNorm; one wave per row
__global__ void ln_kernel(ushortt* __restrict__ buf,
                          const float* __restrict__ g,
                          const float* __restrict__ bb) {
  size_t row = (size_t)blockIdx.x * 4 + (threadIdx.x >> 6);
  int lane = threadIdx.x & 63;
  ushortt* p = buf + row * Aa;
  float v0 = bf2f(p[lane]), v1 = bf2f(p[lane + 64]), v2 = bf2f(p[lane + 128]);
  float s = v0 + v1 + v2;
#pragma unroll
  for (int off = 32; off > 0; off >>= 1) s += __shfl_xor(s, off, 64);
  float m = s * (1.0f / 192.0f);
  float d0 = v0 - m, d1 = v1 - m, d2 = v2 - m;
  float ss = d0 * d0 + d1 * d1 + d2 * d2;
#pragma unroll
  for (int off = 32; off > 0; off >>= 1) ss += __shfl_xor(ss, off, 64);
  float inv = rsqrtf(ss * (1.0f / 192.0f) + 1e-5f);
  p[lane] = f2bf(d0 * inv * g[lane] + bb[lane]);
  p[lane + 64] = f2bf(d1 * inv * g[lane + 64] + bb[lane + 64]);
  p[lane + 128] = f2bf(d2 * inv * g[lane + 128] + bb[lane + 128]);
}

// posmap[bt*Nn + idx[bt,k]] = k+1
__global__ void scatter_pos(const int* __restrict__ idx,
                            short* __restrict__ posmap) {
  int bt = blockIdx.x;
  int k = threadIdx.x;
  if (k < KK) posmap[bt * Nn + idx[bt * KK + k]] = (short)(k + 1);
}

// gate MLP + 3-way softmax; dppart2 has NCH partials per bt
__global__ void gate_kernel(const float* __restrict__ dppart2,
                            const float* __restrict__ appart,
                            const float* __restrict__ w1,
                            const float* __restrict__ b1,
                            const float* __restrict__ w2,
                            const float* __restrict__ b2,
                            float* __restrict__ gw) {
  int b = blockIdx.x;
  __shared__ float sg[2 * Aa];
  __shared__ float sh[Aa];
  int tid = threadIdx.x;
  {
    float d = 0.f;
    for (int t2 = 0; t2 < Tt * NCH; ++t2)
      d += dppart2[(size_t)(b * Tt * NCH + t2) * Aa + tid];
    sg[tid] = d * (1.0f / 3136.0f);
    float a = 0.f;
    for (int k2 = 0; k2 < KK; ++k2) a += appart[(b * KK + k2) * Aa + tid];
    sg[Aa + tid] = a * (1.0f / 128.0f);
  }
  __syncthreads();
  {
    const float* w = w1 + (size_t)tid * 2 * Aa;
    float s = b1[tid];
#pragma unroll 8
    for (int j = 0; j < 2 * Aa; ++j) s = fmaf(sg[j], w[j], s);
    sh[tid] = gelu_f(s);
  }
  __syncthreads();
  float v[3];
#pragma unroll
  for (int i = 0; i < 3; ++i) {
    const float* w = w2 + (size_t)(i * Aa + tid) * Aa;
    float s = b2[i * Aa + tid];
#pragma unroll 8
    for (int j = 0; j < Aa; ++j) s = fmaf(sh[j], w[j], s);
    v[i] = s;
  }
  float mx = fmaxf(v[0], fmaxf(v[1], v[2]));
  float e0 = expf(v[0] - mx), e1 = expf(v[1] - mx), e2 = expf(v[2] - mx);
  float inv = 1.0f / (e0 + e1 + e2);
  gw[(b * 3 + 0) * Aa + tid] = e0 * inv;
  gw[(b * 3 + 1) * Aa + tid] = e1 * inv;
  gw[(b * 3 + 2) * Aa + tid] = e2 * inv;
}

// ============================================================
// fused14 (r17)
// ============================================================
__global__ __launch_bounds__(192) void fused14_kernel(
    const ushortt* __restrict__ local, const ushortt* __restrict__ trans,
    const float* __restrict__ attln, const short* __restrict__ posmap,
    const float* __restrict__ anb, const float* __restrict__ gw,
    ushortt* __restrict__ fused, float* __restrict__ fpart) {
  int blk = blockIdx.x;
  int bt = blk / NCH, chunk = blk - bt * NCH;
  int b = bt >> 4, t = bt & 15;
  int a = threadIdx.x;
  int n0 = chunk * 14;
  float g0 = gw[(b * 3 + 0) * Aa + a];
  float g1 = gw[(b * 3 + 1) * Aa + a];
  float g2 = gw[(b * 3 + 2) * Aa + a];
  float ab = anb[a];
  size_t base = ((size_t)bt * Nn + n0) * Aa + a;
  float acc = 0.f;
  for (int i = 0; i < 14; ++i) {
    size_t o = base + (size_t)i * Aa;
    short pos = posmap[bt * Nn + n0 + i];
    float am = pos ? attln[(((size_t)(b * KK + pos - 1) * Tt) + t) * Aa + a]
                   : ab;
    float f = g0 * bf2f(local[o]) + g1 * bf2f(trans[o]) + g2 * am;
    fused[o] = f2bf(f);
    acc += f;
  }
  fpart[(size_t)blk * Aa + a] = acc;
}

// cls_out: fpart NCH partials
__global__ void cls_kernel(const float* __restrict__ fpart,
                           const float* __restrict__ cw,
                           const float* __restrict__ cb,
                           const float* __restrict__ x,
                           float* __restrict__ out) {
  int bt = blockIdx.x;
  __shared__ float fm[Aa];
  int tid = threadIdx.x;
  if (tid < Aa) {
    float s = 0.f;
    for (int ch = 0; ch < NCH; ++ch)
      s += fpart[(size_t)(bt * NCH + ch) * Aa + tid];
    fm[tid] = s * (1.0f / 196.0f);
  }
  __syncthreads();
  for (int c = tid; c < Cc; c += 256) {
    const float* w = cw + (size_t)c * Aa;
    float s = cb[c];
#pragma unroll 8
    for (int a = 0; a < Aa; ++a) s = fmaf(fm[a], w[a], s);
    size_t off = (size_t)bt * (Nn + 1) * Cc + c;
    out[off] = x[off] + s;
  }
}

// ============================================================
extern "C" void kernel_launch(void* const* d_in, const int* in_sizes, int n_in,
                              void* d_out, int out_size, void* d_ws,
                              size_t ws_size, hipStream_t stream) {
  const float* x = (const float*)d_in[0];
  const float* down_w = (const float*)d_in[1];
  const float* down_b = (const float*)d_in[2];
  const float* ldw_w = (const float*)d_in[3];
  const float* lpw_w = (const float*)d_in[4];
  const float* lnorm_g = (const float*)d_in[5];
  const float* lnorm_b = (const float*)d_in[6];
  const float* tdw_w = (const float*)d_in[7];
  const float* tpw_w = (const float*)d_in[8];
  const float* tmlp_w1 = (const float*)d_in[9];
  const float* tmlp_b1 = (const float*)d_in[10];
  const float* tmlp_w2 = (const float*)d_in[11];
  const float* tmlp_b2 = (const float*)d_in[12];
  const float* tnorm_g = (const float*)d_in[13];
  const float* tnorm_b = (const float*)d_in[14];
  const float* attn_in_w = (const float*)d_in[15];
  const float* attn_in_b = (const float*)d_in[16];
  const float* attn_out_w = (const float*)d_in[17];
  const float* attn_out_b = (const float*)d_in[18];
  const float* aproj_w = (const float*)d_in[19];
  const float* aproj_b = (const float*)d_in[20];
  const float* anorm_g = (const float*)d_in[21];
  const float* anorm_b = (const float*)d_in[22];
  const float* gate_w1 = (const float*)d_in[23];
  const float* gate_b1 = (const float*)d_in[24];
  const float* gate_w2 = (const float*)d_in[25];
  const float* gate_b2 = (const float*)d_in[26];
  const float* up_w = (const float*)d_in[27];
  const float* up_b = (const float*)d_in[28];
  const float* cls_w = (const float*)d_in[29];
  const float* cls_b = (const float*)d_in[30];
  float* out = (float*)d_out;

  float* ws = (float*)d_ws;
  float* W0 = ws;              // ph bf16 -> trp bf16
  float* W1 = W0 + SZ;         // delta bf16 -> transition bf16
  float* W2 = W1 + SZ;         // attn scratch -> locg/trg/h1/fused bf16
  float* W3 = W2 + 2 * SZ;     // local bf16
  float* sal = W3 + SZ;
  float* attout = sal + BTN;
  float* dppart2 = attout + (size_t)BKT * Aa;          // BT*NCH*Aa
  float* appart = dppart2 + (size_t)BT * NCH * Aa;
  float* gw = appart + (size_t)Bb * KK * Aa;
  float* fpart = gw + (size_t)Bb * 3 * Aa;             // BT*NCH*Aa
  double* sal64 = (double*)(fpart + (size_t)BT * NCH * Aa);
  int* cand = (int*)(sal64 + (size_t)BT * NCAND);
  int* idx = cand + (size_t)BT * NCAND;
  float* wT = (float*)(idx + (size_t)BT * KK);
  short* posmap = (short*)(wT + (size_t)Cc * Aa);
  ushortt* wbuf = (ushortt*)(posmap + (size_t)BT * Nn);

  // bf16 weight views
  ushortt* wb_down   = wbuf;
  ushortt* wb_attnin = wbuf + O1;
  ushortt* wb_attnout= wbuf + O2;
  ushortt* wb_aproj  = wbuf + O3;
  ushortt* wb_lpw    = wbuf + O4;
  ushortt* wb_tpw    = wbuf + O5;
  ushortt* wb_t1     = wbuf + O6;
  ushortt* wb_t2     = wbuf + O7;
  ushortt* wb_up     = wbuf + O8;

  // bf16 activation views
  ushortt* ph_b    = (ushortt*)W0;
  ushortt* trp_b   = (ushortt*)W0;
  ushortt* delta_b = (ushortt*)W1;
  ushortt* trans_b = (ushortt*)W1;
  ushortt* locg_b  = (ushortt*)W2;
  ushortt* trg_b   = (ushortt*)W2;
  ushortt* h1_b    = (ushortt*)W2;
  ushortt* fused_b = (ushortt*)W2;
  ushortt* local_b = (ushortt*)W3;

  // attn-phase scratch inside W2 (dead until conv2d)
  ushortt* tok_b = (ushortt*)W2;
  float* qkvb  = W2 + (size_t)BKT * Aa / 2;
  float* obuf  = qkvb + (size_t)BKT * 3 * Aa;
  float* proj1 = obuf + (size_t)BKT * Aa;

  // 0. weights -> bf16, wT for refine
  cvtw_kernel<<<OTOT / 256, 256, 0, stream>>>(
      down_w, attn_in_w, attn_out_w, aproj_w, lpw_w, tpw_w, tmlp_w1,
      tmlp_w2, up_w, wbuf);
  transpose_w<<<(Cc * Aa) / 256, 256, 0, stream>>>(down_w, wT);
  // 1. ph = patch @ down_w.T + down_b (hybrid)
  gemm_hyb<1, ushortt, 1, 0><<<dim3(2, 784), 256, 0, stream>>>(
      x, wb_down, down_b, ph_b, nullptr, BTN, Aa, Cc);
  // 2+3a. delta + dp partials + sal (fused, 14-way parallel)
  delta14_kernel<<<BT * NCH, 192, 0, stream>>>(ph_b, delta_b, dppart2, sal);
  // 3b. candidates -> f64 refine -> exact top-8
  topcand_kernel<<<BT, 64, 0, stream>>>(sal, cand);
  refine_kernel<<<dim3(BT, 2), 192, 0, stream>>>(x, wT, cand, sal64);
  select_kernel<<<BT, 64, 0, stream>>>(sal64, cand, idx);
  // 4. anchor attention
  gather_kernel<<<BKT, Aa, 0, stream>>>(ph_b, delta_b, idx, tok_b);
  gemm_lds<float, 1, 0><<<dim3(6, 32), 256, 0, stream>>>(
      tok_b, wb_attnin, attn_in_b, qkvb, nullptr, BKT, 3 * Aa, Aa);
  attn_core<<<Bb * KK, 256, 0, stream>>>(qkvb, obuf);
  gemm_hyb<0, float, 1, 0><<<dim3(2, 32), 256, 0, stream>>>(
      obuf, wb_attnout, attn_out_b, proj1, nullptr, BKT, Aa, Aa);
  gemm_hyb<0, float, 1, 0><<<dim3(2, 32), 256, 0, stream>>>(
      proj1, wb_aproj, aproj_b, attout, nullptr, BKT, Aa, Aa);
  appart_kernel<<<Bb * KK, Aa, 0, stream>>>(attout, appart);
  // 4b. LN the 2048 anchor rows in place
  ln32_kernel<<<BKT / 4, 256, 0, stream>>>(attout, anorm_g, anorm_b);
  hipMemsetAsync(posmap, 0, (size_t)BT * Nn * sizeof(short), stream);
  scatter_pos<<<BT, 64, 0, stream>>>(idx, posmap);
  // 5. local branch
  conv2d_kernel<<<(unsigned)(SZ / 256), 256, 0, stream>>>(ph_b, ldw_w, locg_b);
  gemm_lds<ushortt, 0, 0><<<dim3(2, 784), 256, 0, stream>>>(
      locg_b, wb_lpw, nullptr, local_b, nullptr, BTN, Aa, Aa);
  ln_kernel<<<BTN / 4, 256, 0, stream>>>(local_b, lnorm_g, lnorm_b);
  // 6. transition branch
  conv1d_kernel<<<(unsigned)(SZ / 256), 256, 0, stream>>>(delta_b, tdw_w, trg_b);
  gemm_lds<ushortt, 0, 0><<<dim3(2, 784), 256, 0, stream>>>(
      trg_b, wb_tpw, nullptr, trp_b, nullptr, BTN, Aa, Aa);
  gemm_lds<ushortt, 1, 1><<<dim3(4, 784), 256, 0, stream>>>(
      trp_b, wb_t1, tmlp_b1, h1_b, nullptr, BTN, 2 * Aa, Aa);
  gemm_lds<ushortt, 1, 0><<<dim3(2, 784), 256, 0, stream>>>(
      h1_b, wb_t2, tmlp_b2, trans_b, nullptr, BTN, Aa, 2 * Aa);
  ln_kernel<<<BTN / 4, 256, 0, stream>>>(trans_b, tnorm_g, tnorm_b);
  // 8. gate
  gate_kernel<<<Bb, Aa, 0, stream>>>(dppart2, appart, gate_w1, gate_b1,
                                     gate_w2, gate_b2, gw);
  // 9. fuse (14-way parallel) + output projections
  fused14_kernel<<<BT * NCH, 192, 0, stream>>>(local_b, trans_b, attout,
                                               posmap, anorm_b, gw, fused_b,
                                               fpart);
  gemm_lds<float, 1, 2><<<dim3(8, 784), 256, 0, stream>>>(
      fused_b, wb_up, up_b, out, x, BTN, Cc, Aa);
  cls_kernel<<<BT, 256, 0, stream>>>(fpart, cls_w, cls_b, x, out);
}